// Round 1
// baseline (505.771 us; speedup 1.0000x reference)
//
#include <hip/hip_runtime.h>
#include <math.h>

#define NI 100000
#define NO 50000
#define NE 100000

// ws layout (float offsets)
#define OFF_WT_OI   0        // 32*288 = 9216  : WT[o*288 + i*8 + a] = Wm_oi[a*1024+i*32+o]; WT[o*288+256+i] = bm_oi[i*32+o]
#define OFF_WT_IO   9216
#define OFF_WRT_OI  18432    // 1024 : WrT[o*32+i] = Wr_oi[i*32+o]
#define OFF_WRT_IO  19456
#define OFF_W2T     20480    // 256  : W2T[i*8+a] = Wm2[a*32+i]
#define OFF_ACC_IND 20736    // NI*32
#define OFF_ACC_ORG (20736 + NI*32)

static constexpr int B_IND  = (NI + 255) / 256;  // 391
static constexpr int B_ORG  = (NO + 255) / 256;  // 196
static constexpr int B_EDGE = (NE + 255) / 256;  // 391

__device__ __forceinline__ float sigmoidf_fast(float x) {
    return 1.0f / (1.0f + __expf(-x));
}

// ---------------------------------------------------------------- prep: weight transposes
__global__ __launch_bounds__(256) void k_prep(
    const float* __restrict__ Wm_oi, const float* __restrict__ bm_oi, const float* __restrict__ Wr_oi,
    const float* __restrict__ Wm_io, const float* __restrict__ bm_io, const float* __restrict__ Wr_io,
    const float* __restrict__ Wm2, float* __restrict__ ws)
{
    int t = blockIdx.x * 256 + threadIdx.x;
    if (t < 9216) {
        int o = t / 288, r = t % 288;
        float v = (r < 256) ? Wm_oi[(r & 7) * 1024 + (r >> 3) * 32 + o]
                            : bm_oi[(r - 256) * 32 + o];
        ws[OFF_WT_OI + t] = v;
    } else if (t < 18432) {
        int u = t - 9216;
        int o = u / 288, r = u % 288;
        float v = (r < 256) ? Wm_io[(r & 7) * 1024 + (r >> 3) * 32 + o]
                            : bm_io[(r - 256) * 32 + o];
        ws[OFF_WT_IO + u] = v;
    } else if (t < 19456) {
        int u = t - 18432;          // u = o*32+i
        ws[OFF_WRT_OI + u] = Wr_oi[(u & 31) * 32 + (u >> 5)];
    } else if (t < 20480) {
        int u = t - 19456;
        ws[OFF_WRT_IO + u] = Wr_io[(u & 31) * 32 + (u >> 5)];
    } else if (t < 20736) {
        int u = t - 20480;          // u = i*8+a
        ws[OFF_W2T + u] = Wm2[(u & 7) * 32 + (u >> 3)];
    }
}

// ---------------------------------------------------------------- root term: acc = x @ Wr + b
__global__ __launch_bounds__(256) void k_root(
    const float* __restrict__ x_ind, const float* __restrict__ x_org,
    const float* __restrict__ ws,
    const float* __restrict__ b_oi, const float* __restrict__ b_io,
    float* __restrict__ acc_ind, float* __restrict__ acc_org)
{
    // blocks [0, B_IND): indivi nodes; [B_IND, B_IND+B_ORG): org nodes.
    const float* x; const float* WrT; const float* bias; float* acc; int n; int N;
    if (blockIdx.x < B_IND) {
        n = blockIdx.x * 256 + threadIdx.x; N = NI;
        x = x_ind; WrT = ws + OFF_WRT_OI; bias = b_oi; acc = acc_ind;
    } else {
        n = (blockIdx.x - B_IND) * 256 + threadIdx.x; N = NO;
        x = x_org; WrT = ws + OFF_WRT_IO; bias = b_io; acc = acc_org;
    }
    if (n >= N) return;
    float xr[32];
    const float4* xp = (const float4*)(x + n * 32);
    #pragma unroll
    for (int q = 0; q < 8; q++) {
        float4 v = xp[q];
        xr[q * 4 + 0] = v.x; xr[q * 4 + 1] = v.y; xr[q * 4 + 2] = v.z; xr[q * 4 + 3] = v.w;
    }
    #pragma unroll 4
    for (int o = 0; o < 32; o++) {
        float s = bias[o];
        #pragma unroll
        for (int i = 0; i < 32; i++) s = fmaf(xr[i], WrT[o * 32 + i], s);
        acc[n * 32 + o] = s;
    }
}

// ---------------------------------------------------------------- layer-1 edge messages (both relations)
__global__ __launch_bounds__(256) void k_edge_l1(
    const int* __restrict__ src_oi, const int* __restrict__ dst_oi, const float* __restrict__ attr_oi,
    const int* __restrict__ src_io, const int* __restrict__ dst_io, const float* __restrict__ attr_io,
    const float* __restrict__ x_ind, const float* __restrict__ x_org,
    const float* __restrict__ ws,
    float* __restrict__ acc_ind, float* __restrict__ acc_org)
{
    // blocks [0, B_EDGE): relation oi (src=org, dst=indivi)
    // blocks [B_EDGE, 2*B_EDGE): relation io (src=indivi, dst=org)
    const int* srcI; const int* dstI; const float* attr; const float* xsrc;
    const float* WT; float* accd; int e;
    if (blockIdx.x < B_EDGE) {
        e = blockIdx.x * 256 + threadIdx.x;
        srcI = src_oi; dstI = dst_oi; attr = attr_oi; xsrc = x_org;
        WT = ws + OFF_WT_OI; accd = acc_ind;
    } else {
        e = (blockIdx.x - B_EDGE) * 256 + threadIdx.x;
        srcI = src_io; dstI = dst_io; attr = attr_io; xsrc = x_ind;
        WT = ws + OFF_WT_IO; accd = acc_org;
    }
    if (e >= NE) return;

    int s = srcI[e];
    int d = dstI[e];

    float xr[32];
    const float4* xp = (const float4*)(xsrc + s * 32);
    #pragma unroll
    for (int q = 0; q < 8; q++) {
        float4 v = xp[q];
        xr[q * 4 + 0] = v.x; xr[q * 4 + 1] = v.y; xr[q * 4 + 2] = v.z; xr[q * 4 + 3] = v.w;
    }
    float ar[8];
    const float4* ap = (const float4*)(attr + e * 8);
    {
        float4 v0 = ap[0], v1 = ap[1];
        ar[0] = v0.x; ar[1] = v0.y; ar[2] = v0.z; ar[3] = v0.w;
        ar[4] = v1.x; ar[5] = v1.y; ar[6] = v1.z; ar[7] = v1.w;
    }

    // msg[o] = sum_i xr[i] * ( bm[i*32+o] + sum_a ar[a]*Wm[a][i*32+o] )
    // WT row per o: [i*8+a] weights, [256+i] bias — all wave-uniform -> scalar loads.
    #pragma unroll 2
    for (int o = 0; o < 32; o++) {
        const float* w = WT + o * 288;
        float macc = 0.0f;
        #pragma unroll
        for (int i = 0; i < 32; i++) {
            float tt = w[256 + i];
            #pragma unroll
            for (int a = 0; a < 8; a++) tt = fmaf(ar[a], w[i * 8 + a], tt);
            macc = fmaf(xr[i], tt, macc);
        }
        atomicAdd(accd + d * 32 + o, macc);
    }
}

// ---------------------------------------------------------------- sigmoid epilogue + layer-2 root
__global__ __launch_bounds__(256) void k_sig(
    float* __restrict__ acc_ind, float* __restrict__ acc_org,
    const float* __restrict__ Wr2, const float* __restrict__ b2,
    float* __restrict__ out)
{
    if (blockIdx.x < B_IND) {
        int n = blockIdx.x * 256 + threadIdx.x;
        if (n >= NI) return;
        float h[32];
        float4* rp = (float4*)(acc_ind + n * 32);
        #pragma unroll
        for (int q = 0; q < 8; q++) {
            float4 v = rp[q];
            h[q * 4 + 0] = sigmoidf_fast(v.x); h[q * 4 + 1] = sigmoidf_fast(v.y);
            h[q * 4 + 2] = sigmoidf_fast(v.z); h[q * 4 + 3] = sigmoidf_fast(v.w);
            float4 w = make_float4(h[q * 4 + 0], h[q * 4 + 1], h[q * 4 + 2], h[q * 4 + 3]);
            rp[q] = w;
        }
        float s = b2[0];
        #pragma unroll
        for (int i = 0; i < 32; i++) s = fmaf(h[i], Wr2[i], s);
        out[n] = s;   // pre-sigmoid accumulator for layer 2
    } else {
        int n = (blockIdx.x - B_IND) * 256 + threadIdx.x;
        if (n >= NO) return;
        float4* rp = (float4*)(acc_org + n * 32);
        #pragma unroll
        for (int q = 0; q < 8; q++) {
            float4 v = rp[q];
            v.x = sigmoidf_fast(v.x); v.y = sigmoidf_fast(v.y);
            v.z = sigmoidf_fast(v.z); v.w = sigmoidf_fast(v.w);
            rp[q] = v;
        }
    }
}

// ---------------------------------------------------------------- layer-2 edge messages (oi edges)
__global__ __launch_bounds__(256) void k_edge_l2(
    const int* __restrict__ src_oi, const int* __restrict__ dst_oi, const float* __restrict__ attr_oi,
    const float* __restrict__ h_org,   // acc_org post-sigmoid
    const float* __restrict__ ws,      // W2T
    const float* __restrict__ bm2,
    float* __restrict__ out)
{
    int e = blockIdx.x * 256 + threadIdx.x;
    if (e >= NE) return;
    int s = src_oi[e];
    int d = dst_oi[e];

    float hr[32];
    const float4* hp = (const float4*)(h_org + s * 32);
    #pragma unroll
    for (int q = 0; q < 8; q++) {
        float4 v = hp[q];
        hr[q * 4 + 0] = v.x; hr[q * 4 + 1] = v.y; hr[q * 4 + 2] = v.z; hr[q * 4 + 3] = v.w;
    }
    float ar[8];
    const float4* ap = (const float4*)(attr_oi + e * 8);
    {
        float4 v0 = ap[0], v1 = ap[1];
        ar[0] = v0.x; ar[1] = v0.y; ar[2] = v0.z; ar[3] = v0.w;
        ar[4] = v1.x; ar[5] = v1.y; ar[6] = v1.z; ar[7] = v1.w;
    }
    const float* W2T = ws + OFF_W2T;
    float msg = 0.0f;
    #pragma unroll
    for (int i = 0; i < 32; i++) {
        float tt = bm2[i];
        #pragma unroll
        for (int a = 0; a < 8; a++) tt = fmaf(ar[a], W2T[i * 8 + a], tt);
        msg = fmaf(hr[i], tt, msg);
    }
    atomicAdd(out + d, msg);
}

// ---------------------------------------------------------------- final sigmoid on output
__global__ __launch_bounds__(256) void k_sig_out(float* __restrict__ out)
{
    int t = blockIdx.x * 256 + threadIdx.x;
    if (t < NI) out[t] = sigmoidf_fast(out[t]);
}

extern "C" void kernel_launch(void* const* d_in, const int* in_sizes, int n_in,
                              void* d_out, int out_size, void* d_ws, size_t ws_size,
                              hipStream_t stream)
{
    const float* x_ind   = (const float*)d_in[0];
    const float* x_org   = (const float*)d_in[1];
    const int*   src_oi  = (const int*)d_in[2];
    const int*   dst_oi  = (const int*)d_in[3];
    const float* attr_oi = (const float*)d_in[4];
    const int*   src_io  = (const int*)d_in[5];
    const int*   dst_io  = (const int*)d_in[6];
    const float* attr_io = (const float*)d_in[7];
    const float* Wm_oi   = (const float*)d_in[8];
    const float* bm_oi   = (const float*)d_in[9];
    const float* Wr_oi   = (const float*)d_in[10];
    const float* b_oi    = (const float*)d_in[11];
    const float* Wm_io   = (const float*)d_in[12];
    const float* bm_io   = (const float*)d_in[13];
    const float* Wr_io   = (const float*)d_in[14];
    const float* b_io    = (const float*)d_in[15];
    const float* Wm2     = (const float*)d_in[16];
    const float* bm2     = (const float*)d_in[17];
    const float* Wr2     = (const float*)d_in[18];
    const float* b2      = (const float*)d_in[19];

    float* ws      = (float*)d_ws;
    float* acc_ind = ws + OFF_ACC_IND;
    float* acc_org = ws + OFF_ACC_ORG;
    float* out     = (float*)d_out;

    k_prep<<<(20736 + 255) / 256, 256, 0, stream>>>(
        Wm_oi, bm_oi, Wr_oi, Wm_io, bm_io, Wr_io, Wm2, ws);

    k_root<<<B_IND + B_ORG, 256, 0, stream>>>(
        x_ind, x_org, ws, b_oi, b_io, acc_ind, acc_org);

    k_edge_l1<<<2 * B_EDGE, 256, 0, stream>>>(
        src_oi, dst_oi, attr_oi, src_io, dst_io, attr_io,
        x_ind, x_org, ws, acc_ind, acc_org);

    k_sig<<<B_IND + B_ORG, 256, 0, stream>>>(acc_ind, acc_org, Wr2, b2, out);

    k_edge_l2<<<B_EDGE, 256, 0, stream>>>(
        src_oi, dst_oi, attr_oi, acc_org, ws, bm2, out);

    k_sig_out<<<B_IND, 256, 0, stream>>>(out);
}

// Round 2
// 252.913 us; speedup vs baseline: 1.9998x; 1.9998x over previous
//
#include <hip/hip_runtime.h>
#include <math.h>

#define NI 100000
#define NO 50000
#define NE 100000
#define NB (NI + NO)          // 150000 combined dst bins
#define TOTE (2 * NE)         // 200000

// ---- ws layout (float/int offsets, 4B units) ----
#define OFF_WT_OI    0         // 9216
#define OFF_WT_IO    9216      // 9216
#define OFF_WRT_OI   18432     // 1024
#define OFF_WRT_IO   19456     // 1024
#define OFF_Y2Z2     20480     // 50000*12 = 600000
#define OFF_SCANNED  620480    // 150016 ints
#define OFF_BLOCKSUM 770496    // 640 ints
#define OFF_BLOCKPREF 771136   // 640 ints
#define OFF_SORTED   771776    // 200000 ints
#define OFF_DSTS     971776    // 200000 ints
#define OFF_ACC      1171776   // 150000*32 floats = 4800000   (zeroed)
#define OFF_CNT      5971776   // 150016 ints                  (zeroed)
#define OFF_CNT2     6121792   // 150016 ints                  (zeroed)
#define ZERO_COUNT   (4800000 + 2 * 150016)   // floats/ints to memset from OFF_ACC

static constexpr int B_EDGE = (NE + 255) / 256;    // 391 blocks per relation
static constexpr int B_IND  = (NI + 255) / 256;    // 391
static constexpr int B_ORG  = (NO + 255) / 256;    // 196
static constexpr int SCAN_BLOCKS = (NB + 255) / 256;  // 586

__device__ __forceinline__ float sigmoidf_fast(float x) {
    return 1.0f / (1.0f + __expf(-x));
}

// ---------------------------------------------------------------- prep: weight transposes
__global__ __launch_bounds__(256) void k_prep(
    const float* __restrict__ Wm_oi, const float* __restrict__ bm_oi, const float* __restrict__ Wr_oi,
    const float* __restrict__ Wm_io, const float* __restrict__ bm_io, const float* __restrict__ Wr_io,
    float* __restrict__ ws)
{
    int t = blockIdx.x * 256 + threadIdx.x;
    if (t < 9216) {
        int o = t / 288, r = t % 288;
        float v = (r < 256) ? Wm_oi[(r & 7) * 1024 + (r >> 3) * 32 + o]
                            : bm_oi[(r - 256) * 32 + o];
        ws[OFF_WT_OI + t] = v;
    } else if (t < 18432) {
        int u = t - 9216;
        int o = u / 288, r = u % 288;
        float v = (r < 256) ? Wm_io[(r & 7) * 1024 + (r >> 3) * 32 + o]
                            : bm_io[(r - 256) * 32 + o];
        ws[OFF_WT_IO + u] = v;
    } else if (t < 19456) {
        int u = t - 18432;          // u = o*32+i
        ws[OFF_WRT_OI + u] = Wr_oi[(u & 31) * 32 + (u >> 5)];
    } else if (t < 20480) {
        int u = t - 19456;
        ws[OFF_WRT_IO + u] = Wr_io[(u & 31) * 32 + (u >> 5)];
    }
}

// ---------------------------------------------------------------- histogram of combined dst
__global__ __launch_bounds__(256) void k_hist(
    const int* __restrict__ dst_oi, const int* __restrict__ dst_io,
    int* __restrict__ cnt)
{
    bool is_io = blockIdx.x >= B_EDGE;
    int e = (is_io ? (blockIdx.x - B_EDGE) : blockIdx.x) * 256 + threadIdx.x;
    if (e >= NE) return;
    int cd = is_io ? (NI + dst_io[e]) : dst_oi[e];
    atomicAdd(&cnt[cd], 1);
}

// ---------------------------------------------------------------- block-level exclusive scan
__global__ __launch_bounds__(256) void k_scan_block(
    const int* __restrict__ cnt, int* __restrict__ scanned, int* __restrict__ blocksum)
{
    int d = blockIdx.x * 256 + threadIdx.x;
    int v = (d < NB) ? cnt[d] : 0;
    int lane = threadIdx.x & 63, wv = threadIdx.x >> 6;
    int s = v;
    #pragma unroll
    for (int off = 1; off < 64; off <<= 1) {
        int t = __shfl_up(s, off);
        if (lane >= off) s += t;
    }
    __shared__ int wsum[4];
    if (lane == 63) wsum[wv] = s;
    __syncthreads();
    int add = 0;
    for (int w = 0; w < wv; w++) add += wsum[w];
    int incl = s + add;
    scanned[d] = incl - v;                 // exclusive within block (d<150016 always in-bounds)
    if (threadIdx.x == 255) blocksum[blockIdx.x] = incl;
}

// ---------------------------------------------------------------- top-level scan of block sums
__global__ __launch_bounds__(1024) void k_scan_top(
    const int* __restrict__ blocksum, int* __restrict__ blockpref)
{
    __shared__ int L[1024];
    int t = threadIdx.x;
    int v = (t < SCAN_BLOCKS) ? blocksum[t] : 0;
    L[t] = v;
    __syncthreads();
    for (int off = 1; off < 1024; off <<= 1) {
        int u = (t >= off) ? L[t - off] : 0;
        __syncthreads();
        L[t] += u;
        __syncthreads();
    }
    if (t < SCAN_BLOCKS) blockpref[t] = L[t] - v;   // exclusive
}

// ---------------------------------------------------------------- scatter edges into sorted order
__global__ __launch_bounds__(256) void k_scatter(
    const int* __restrict__ dst_oi, const int* __restrict__ dst_io,
    const int* __restrict__ scanned, const int* __restrict__ blockpref,
    int* __restrict__ cnt2, int* __restrict__ sorted_eid, int* __restrict__ dstsorted)
{
    bool is_io = blockIdx.x >= B_EDGE;
    int e = (is_io ? (blockIdx.x - B_EDGE) : blockIdx.x) * 256 + threadIdx.x;
    if (e >= NE) return;
    int cd = is_io ? (NI + dst_io[e]) : dst_oi[e];
    int base = scanned[cd] + blockpref[cd >> 8];
    int pos = base + atomicAdd(&cnt2[cd], 1);
    sorted_eid[pos] = e;          // raw edge id; relation implied by pos (<NE: oi, >=NE: io)
    dstsorted[pos] = cd;
}

// ---------------------------------------------------------------- layer-1 edge messages, sorted order
__global__ __launch_bounds__(256) void k_edge(
    const int* __restrict__ src_oi, const float* __restrict__ attr_oi,
    const int* __restrict__ src_io, const float* __restrict__ attr_io,
    const float* __restrict__ x_ind, const float* __restrict__ x_org,
    const float* __restrict__ ws,
    const int* __restrict__ sorted_eid, const int* __restrict__ dstsorted,
    float* __restrict__ acc)
{
    __shared__ float stage[256 * 36];   // 36 KB, float4-aligned rows
    bool is_io = blockIdx.x >= B_EDGE;
    int blockStart = is_io ? (NE + (blockIdx.x - B_EDGE) * 256) : (blockIdx.x * 256);
    int relEnd = is_io ? TOTE : NE;
    int p = blockStart + (int)threadIdx.x;
    bool act = p < relEnd;

    const float* WT   = ws + (is_io ? OFF_WT_IO : OFF_WT_OI);
    const float* xsrc = is_io ? x_ind : x_org;
    const int*   srcA = is_io ? src_io : src_oi;
    const float* attrA = is_io ? attr_io : attr_oi;

    int cd = -1;
    float msg[32];
    if (act) {
        cd = dstsorted[p];
        int e = sorted_eid[p];
        int s = srcA[e];

        float xr[32];
        const float4* xp = (const float4*)(xsrc + s * 32);
        #pragma unroll
        for (int q = 0; q < 8; q++) {
            float4 v = xp[q];
            xr[q * 4 + 0] = v.x; xr[q * 4 + 1] = v.y; xr[q * 4 + 2] = v.z; xr[q * 4 + 3] = v.w;
        }
        float ar[8];
        const float4* ap = (const float4*)(attrA + e * 8);
        {
            float4 v0 = ap[0], v1 = ap[1];
            ar[0] = v0.x; ar[1] = v0.y; ar[2] = v0.z; ar[3] = v0.w;
            ar[4] = v1.x; ar[5] = v1.y; ar[6] = v1.z; ar[7] = v1.w;
        }
        // msg[o] = sum_i xr[i] * ( bm[i,o] + sum_a ar[a]*Wm[a,i,o] ); weights wave-uniform -> scalar loads
        #pragma unroll 2
        for (int o = 0; o < 32; o++) {
            const float* w = WT + o * 288;
            float macc = 0.0f;
            #pragma unroll
            for (int i = 0; i < 32; i++) {
                float tt = w[256 + i];
                #pragma unroll
                for (int a = 0; a < 8; a++) tt = fmaf(ar[a], w[i * 8 + a], tt);
                macc = fmaf(xr[i], tt, macc);
            }
            msg[o] = macc;
        }
        float4* srow = (float4*)(stage + threadIdx.x * 36);
        #pragma unroll
        for (int q = 0; q < 8; q++)
            srow[q] = make_float4(msg[q * 4 + 0], msg[q * 4 + 1], msg[q * 4 + 2], msg[q * 4 + 3]);
    }
    __syncthreads();

    // phase 2: per-dst segment reduction within block; sorted dst => coalesced dense writes
    bool head = act && (p == blockStart || dstsorted[p - 1] != cd);
    if (head) {
        int blockEnd = min(blockStart + 256, relEnd);
        int q = p + 1;
        while (q < blockEnd && dstsorted[q] == cd) {
            const float4* rrow = (const float4*)(stage + (q - blockStart) * 36);
            #pragma unroll
            for (int j = 0; j < 8; j++) {
                float4 v = rrow[j];
                msg[j * 4 + 0] += v.x; msg[j * 4 + 1] += v.y;
                msg[j * 4 + 2] += v.z; msg[j * 4 + 3] += v.w;
            }
            q++;
        }
        bool openR = (q == blockEnd) && (q < TOTE) && (dstsorted[q] == cd);
        bool openL = (p == blockStart) && (p > 0) && (dstsorted[p - 1] == cd);
        float* dp = acc + cd * 32;
        if (openL || openR) {
            #pragma unroll
            for (int o = 0; o < 32; o++) atomicAdd(dp + o, msg[o]);
        } else {
            float4* dp4 = (float4*)dp;
            #pragma unroll
            for (int j = 0; j < 8; j++)
                dp4[j] = make_float4(msg[j * 4 + 0], msg[j * 4 + 1], msg[j * 4 + 2], msg[j * 4 + 3]);
        }
    }
}

// ---------------------------------------------------------------- finish layer 1: +root, sigmoid; prep layer 2
__global__ __launch_bounds__(256) void k_finish(
    const float* __restrict__ x_ind, const float* __restrict__ x_org,
    const float* __restrict__ ws, const float* __restrict__ acc,
    const float* __restrict__ b_oi, const float* __restrict__ b_io,
    const float* __restrict__ Wm2, const float* __restrict__ bm2,
    const float* __restrict__ Wr2, const float* __restrict__ b2,
    float* __restrict__ y2z2, float* __restrict__ out)
{
    bool is_org = blockIdx.x >= B_IND;
    int n = (is_org ? (blockIdx.x - B_IND) : blockIdx.x) * 256 + threadIdx.x;
    int N = is_org ? NO : NI;
    if (n >= N) return;
    int cd = is_org ? (NI + n) : n;

    const float* x    = is_org ? x_org : x_ind;
    const float* WrT  = ws + (is_org ? OFF_WRT_IO : OFF_WRT_OI);
    const float* bias = is_org ? b_io : b_oi;

    float xr[32];
    const float4* xp = (const float4*)(x + n * 32);
    #pragma unroll
    for (int q = 0; q < 8; q++) {
        float4 v = xp[q];
        xr[q * 4 + 0] = v.x; xr[q * 4 + 1] = v.y; xr[q * 4 + 2] = v.z; xr[q * 4 + 3] = v.w;
    }
    float h[32];
    const float4* aprow = (const float4*)(acc + cd * 32);
    #pragma unroll
    for (int q = 0; q < 8; q++) {
        float4 v = aprow[q];
        h[q * 4 + 0] = v.x; h[q * 4 + 1] = v.y; h[q * 4 + 2] = v.z; h[q * 4 + 3] = v.w;
    }
    #pragma unroll 4
    for (int o = 0; o < 32; o++) {
        float s = bias[o] + h[o];
        #pragma unroll
        for (int i = 0; i < 32; i++) s = fmaf(xr[i], WrT[o * 32 + i], s);
        h[o] = sigmoidf_fast(s);
    }
    if (!is_org) {
        // layer-2 root (pre-sigmoid), staged in out[]
        float s = b2[0];
        #pragma unroll
        for (int i = 0; i < 32; i++) s = fmaf(h[i], Wr2[i], s);
        out[n] = s;
    } else {
        // layer-2 per-src factorization: z2 = h·bm2 ; y2[a] = sum_i h[i]*Wm2[a*32+i]
        float z2 = 0.0f;
        #pragma unroll
        for (int i = 0; i < 32; i++) z2 = fmaf(h[i], bm2[i], z2);
        float* yz = y2z2 + n * 12;
        yz[0] = z2;
        #pragma unroll
        for (int a = 0; a < 8; a++) {
            float s = 0.0f;
            #pragma unroll
            for (int i = 0; i < 32; i++) s = fmaf(h[i], Wm2[a * 32 + i], s);
            yz[1 + a] = s;
        }
    }
}

// ---------------------------------------------------------------- layer 2: CSR gather per indivi node
__global__ __launch_bounds__(256) void k_out(
    const int* __restrict__ src_oi, const float* __restrict__ attr_oi,
    const int* __restrict__ scanned, const int* __restrict__ blockpref,
    const int* __restrict__ sorted_eid, const float* __restrict__ y2z2,
    float* __restrict__ out)
{
    int d = blockIdx.x * 256 + threadIdx.x;
    if (d >= NI) return;
    int base = scanned[d] + blockpref[d >> 8];
    int next = scanned[d + 1] + blockpref[(d + 1) >> 8];   // d+1 <= NI < 150016, valid
    float t = out[d];                                      // layer-2 root, pre-sigmoid
    for (int p = base; p < next; p++) {
        int e = sorted_eid[p];                             // oi edge (bins < NI)
        int s = src_oi[e];
        const float* yz = y2z2 + s * 12;
        const float4* ap = (const float4*)(attr_oi + e * 8);
        float4 a0 = ap[0], a1 = ap[1];
        float m = yz[0];
        m = fmaf(a0.x, yz[1], m); m = fmaf(a0.y, yz[2], m);
        m = fmaf(a0.z, yz[3], m); m = fmaf(a0.w, yz[4], m);
        m = fmaf(a1.x, yz[5], m); m = fmaf(a1.y, yz[6], m);
        m = fmaf(a1.z, yz[7], m); m = fmaf(a1.w, yz[8], m);
        t += m;
    }
    out[d] = sigmoidf_fast(t);
}

// ---------------------------------------------------------------- launch
extern "C" void kernel_launch(void* const* d_in, const int* in_sizes, int n_in,
                              void* d_out, int out_size, void* d_ws, size_t ws_size,
                              hipStream_t stream)
{
    const float* x_ind   = (const float*)d_in[0];
    const float* x_org   = (const float*)d_in[1];
    const int*   src_oi  = (const int*)d_in[2];
    const int*   dst_oi  = (const int*)d_in[3];
    const float* attr_oi = (const float*)d_in[4];
    const int*   src_io  = (const int*)d_in[5];
    const int*   dst_io  = (const int*)d_in[6];
    const float* attr_io = (const float*)d_in[7];
    const float* Wm_oi   = (const float*)d_in[8];
    const float* bm_oi   = (const float*)d_in[9];
    const float* Wr_oi   = (const float*)d_in[10];
    const float* b_oi    = (const float*)d_in[11];
    const float* Wm_io   = (const float*)d_in[12];
    const float* bm_io   = (const float*)d_in[13];
    const float* Wr_io   = (const float*)d_in[14];
    const float* b_io    = (const float*)d_in[15];
    const float* Wm2     = (const float*)d_in[16];
    const float* bm2     = (const float*)d_in[17];
    const float* Wr2     = (const float*)d_in[18];
    const float* b2      = (const float*)d_in[19];

    float* ws        = (float*)d_ws;
    float* y2z2      = ws + OFF_Y2Z2;
    int*   scanned   = (int*)(ws + OFF_SCANNED);
    int*   blocksum  = (int*)(ws + OFF_BLOCKSUM);
    int*   blockpref = (int*)(ws + OFF_BLOCKPREF);
    int*   sorted    = (int*)(ws + OFF_SORTED);
    int*   dsts      = (int*)(ws + OFF_DSTS);
    float* acc       = ws + OFF_ACC;
    int*   cnt       = (int*)(ws + OFF_CNT);
    int*   cnt2      = (int*)(ws + OFF_CNT2);
    float* out       = (float*)d_out;

    // zero acc + cnt + cnt2 (contiguous region)
    hipMemsetAsync(ws + OFF_ACC, 0, (size_t)ZERO_COUNT * 4, stream);

    k_prep<<<(20480 + 255) / 256, 256, 0, stream>>>(
        Wm_oi, bm_oi, Wr_oi, Wm_io, bm_io, Wr_io, ws);

    k_hist<<<2 * B_EDGE, 256, 0, stream>>>(dst_oi, dst_io, cnt);

    k_scan_block<<<SCAN_BLOCKS, 256, 0, stream>>>(cnt, scanned, blocksum);

    k_scan_top<<<1, 1024, 0, stream>>>(blocksum, blockpref);

    k_scatter<<<2 * B_EDGE, 256, 0, stream>>>(
        dst_oi, dst_io, scanned, blockpref, cnt2, sorted, dsts);

    k_edge<<<2 * B_EDGE, 256, 0, stream>>>(
        src_oi, attr_oi, src_io, attr_io, x_ind, x_org, ws, sorted, dsts, acc);

    k_finish<<<B_IND + B_ORG, 256, 0, stream>>>(
        x_ind, x_org, ws, acc, b_oi, b_io, Wm2, bm2, Wr2, b2, y2z2, out);

    k_out<<<B_IND, 256, 0, stream>>>(
        src_oi, attr_oi, scanned, blockpref, sorted, y2z2, out);
}